// Round 12
// baseline (634.169 us; speedup 1.0000x reference)
//
#include <hip/hip_runtime.h>
#include <math.h>

#define D 128

// M[j][k] = sum_i Wq[i][j] * Wk[i][k]   (so scores = mean^T M x)
// WoT[j][k] = Wo[k][j]                  (so out[s] = y[s] @ WoT)
__global__ void k_prep(const float* __restrict__ Wq, const float* __restrict__ Wk,
                       const float* __restrict__ Wo, float* __restrict__ M,
                       float* __restrict__ WoT) {
  int j = blockIdx.x, k = threadIdx.x;
  float acc = 0.f;
#pragma unroll 8
  for (int i = 0; i < D; ++i) acc = fmaf(Wq[i * D + j], Wk[i * D + k], acc);
  M[j * D + k] = acc;
  WoT[j * D + k] = Wo[k * D + j];
}

// starts[s] = first element index of segment s; starts[S] = V. idx is sorted.
__global__ void k_starts(const int* __restrict__ idx, int* __restrict__ starts,
                         int V, int S) {
  int v = blockIdx.x * blockDim.x + threadIdx.x;
  if (v >= V) return;
  int c = idx[v];
  int p = (v == 0) ? -1 : idx[v - 1];
  for (int s = p + 1; s <= c; ++s) starts[s] = v;
  if (v == V - 1) {
    for (int s = c + 1; s <= S; ++s) starts[s] = V;
  }
}

// ---------- REAL PIPELINE (R4 verbatim, best known = 258us) ----------

__global__ void k_means(const float* __restrict__ x, const int* __restrict__ starts,
                        float* __restrict__ mean, int S) {
  int tid = blockIdx.x * blockDim.x + threadIdx.x;
  if (tid >= S * 32) return;
  int s = tid >> 5, g = tid & 31;
  int b = starts[s], e = starts[s + 1];
  int n = e - b;
  const float4* xp = (const float4*)(x + (size_t)b * D) + g;
  float4 a = make_float4(0.f, 0.f, 0.f, 0.f);
  for (int v = 0; v < n; v += 4) {
    int rem = n - v;
    const float4* p = xp + (size_t)v * (D / 4);
    float4 r0 = p[0];
    float4 r1 = p[(rem > 1) ? (D / 4) : 0];
    float4 r2 = p[(rem > 2) ? (2 * D / 4) : 0];
    float4 r3 = p[(rem > 3) ? (3 * D / 4) : 0];
    float m1 = (rem > 1) ? 1.f : 0.f;
    float m2 = (rem > 2) ? 1.f : 0.f;
    float m3 = (rem > 3) ? 1.f : 0.f;
    a.x += r0.x; a.y += r0.y; a.z += r0.z; a.w += r0.w;
    a.x = fmaf(m1, r1.x, a.x); a.y = fmaf(m1, r1.y, a.y);
    a.z = fmaf(m1, r1.z, a.z); a.w = fmaf(m1, r1.w, a.w);
    a.x = fmaf(m2, r2.x, a.x); a.y = fmaf(m2, r2.y, a.y);
    a.z = fmaf(m2, r2.z, a.z); a.w = fmaf(m2, r2.w, a.w);
    a.x = fmaf(m3, r3.x, a.x); a.y = fmaf(m3, r3.y, a.y);
    a.z = fmaf(m3, r3.z, a.z); a.w = fmaf(m3, r3.w, a.w);
  }
  float inv = (n > 0) ? 1.f / (float)n : 0.f;
  a.x *= inv; a.y *= inv; a.z *= inv; a.w *= inv;
  *(float4*)(mean + (size_t)s * D + g * 4) = a;
}

__global__ void k_rowmat4(const float* __restrict__ in, const float* __restrict__ B,
                          float* __restrict__ out, int S) {
  __shared__ float Bl[D * D];
  for (int i = threadIdx.x; i < D * D / 4; i += (int)blockDim.x)
    ((float4*)Bl)[i] = ((const float4*)B)[i];
  __syncthreads();
  int t = blockIdx.x * blockDim.x + threadIdx.x;
  int g = t & 31;
  int s0 = (t >> 5) * 4;
  if (s0 >= S) return;
  int nr = S - s0; nr = nr > 4 ? 4 : nr;
  float4 a0 = make_float4(0, 0, 0, 0), a1 = a0, a2 = a0, a3 = a0;
  const float4* r0 = (const float4*)(in + (size_t)s0 * D);
  const float4* r1 = (const float4*)(in + (size_t)(s0 + 1) * D);
  const float4* r2 = (const float4*)(in + (size_t)(s0 + 2) * D);
  const float4* r3 = (const float4*)(in + (size_t)(s0 + 3) * D);
#pragma unroll 4
  for (int j4 = 0; j4 < D / 4; ++j4) {
    float4 b0 = *(const float4*)(Bl + (j4 * 4 + 0) * D + g * 4);
    float4 b1 = *(const float4*)(Bl + (j4 * 4 + 1) * D + g * 4);
    float4 b2 = *(const float4*)(Bl + (j4 * 4 + 2) * D + g * 4);
    float4 b3 = *(const float4*)(Bl + (j4 * 4 + 3) * D + g * 4);
#define ROWFMA(ar, rr)                                                   \
    {                                                                    \
      float4 m = rr[j4];                                                 \
      ar.x = fmaf(m.x, b0.x, ar.x); ar.y = fmaf(m.x, b0.y, ar.y);        \
      ar.z = fmaf(m.x, b0.z, ar.z); ar.w = fmaf(m.x, b0.w, ar.w);        \
      ar.x = fmaf(m.y, b1.x, ar.x); ar.y = fmaf(m.y, b1.y, ar.y);        \
      ar.z = fmaf(m.y, b1.z, ar.z); ar.w = fmaf(m.y, b1.w, ar.w);        \
      ar.x = fmaf(m.z, b2.x, ar.x); ar.y = fmaf(m.z, b2.y, ar.y);        \
      ar.z = fmaf(m.z, b2.z, ar.z); ar.w = fmaf(m.z, b2.w, ar.w);        \
      ar.x = fmaf(m.w, b3.x, ar.x); ar.y = fmaf(m.w, b3.y, ar.y);        \
      ar.z = fmaf(m.w, b3.z, ar.z); ar.w = fmaf(m.w, b3.w, ar.w);        \
    }
    ROWFMA(a0, r0);
    if (nr > 1) ROWFMA(a1, r1);
    if (nr > 2) ROWFMA(a2, r2);
    if (nr > 3) ROWFMA(a3, r3);
#undef ROWFMA
  }
  *(float4*)(out + (size_t)s0 * D + g * 4) = a0;
  if (nr > 1) *(float4*)(out + (size_t)(s0 + 1) * D + g * 4) = a1;
  if (nr > 2) *(float4*)(out + (size_t)(s0 + 2) * D + g * 4) = a2;
  if (nr > 3) *(float4*)(out + (size_t)(s0 + 3) * D + g * 4) = a3;
}

__global__ void k_score_y(const float* __restrict__ x, const int* __restrict__ starts,
                          const float* __restrict__ t, float* __restrict__ y, int S) {
  int tid = blockIdx.x * blockDim.x + threadIdx.x;
  if (tid >= S * 32) return;
  int s = tid >> 5, g = tid & 31;
  int b = starts[s], e = starts[s + 1];
  int n = e - b;
  float4 t4 = *(const float4*)(t + (size_t)s * D + g * 4);
  const float4* xp = (const float4*)(x + (size_t)b * D) + g;
  float4 a = make_float4(0.f, 0.f, 0.f, 0.f);
  float den = 0.f;
  for (int v = 0; v < n; v += 4) {
    int rem = n - v;
    const float4* p = xp + (size_t)v * (D / 4);
    float4 r0 = p[0];
    float4 r1 = p[(rem > 1) ? (D / 4) : 0];
    float4 r2 = p[(rem > 2) ? (2 * D / 4) : 0];
    float4 r3 = p[(rem > 3) ? (3 * D / 4) : 0];
    float d0 = t4.x * r0.x + t4.y * r0.y + t4.z * r0.z + t4.w * r0.w;
    float d1 = t4.x * r1.x + t4.y * r1.y + t4.z * r1.z + t4.w * r1.w;
    float d2 = t4.x * r2.x + t4.y * r2.y + t4.z * r2.z + t4.w * r2.w;
    float d3 = t4.x * r3.x + t4.y * r3.y + t4.z * r3.z + t4.w * r3.w;
    d0 += __shfl_xor(d0, 16); d1 += __shfl_xor(d1, 16);
    d2 += __shfl_xor(d2, 16); d3 += __shfl_xor(d3, 16);
    d0 += __shfl_xor(d0, 8);  d1 += __shfl_xor(d1, 8);
    d2 += __shfl_xor(d2, 8);  d3 += __shfl_xor(d3, 8);
    d0 += __shfl_xor(d0, 4);  d1 += __shfl_xor(d1, 4);
    d2 += __shfl_xor(d2, 4);  d3 += __shfl_xor(d3, 4);
    d0 += __shfl_xor(d0, 2);  d1 += __shfl_xor(d1, 2);
    d2 += __shfl_xor(d2, 2);  d3 += __shfl_xor(d3, 2);
    d0 += __shfl_xor(d0, 1);  d1 += __shfl_xor(d1, 1);
    d2 += __shfl_xor(d2, 1);  d3 += __shfl_xor(d3, 1);
    float w0 = __expf(d0);
    float w1 = (rem > 1) ? __expf(d1) : 0.f;
    float w2 = (rem > 2) ? __expf(d2) : 0.f;
    float w3 = (rem > 3) ? __expf(d3) : 0.f;
    den += w0 + w1 + w2 + w3;
    a.x = fmaf(w0, r0.x, a.x); a.y = fmaf(w0, r0.y, a.y);
    a.z = fmaf(w0, r0.z, a.z); a.w = fmaf(w0, r0.w, a.w);
    a.x = fmaf(w1, r1.x, a.x); a.y = fmaf(w1, r1.y, a.y);
    a.z = fmaf(w1, r1.z, a.z); a.w = fmaf(w1, r1.w, a.w);
    a.x = fmaf(w2, r2.x, a.x); a.y = fmaf(w2, r2.y, a.y);
    a.z = fmaf(w2, r2.z, a.z); a.w = fmaf(w2, r2.w, a.w);
    a.x = fmaf(w3, r3.x, a.x); a.y = fmaf(w3, r3.y, a.y);
    a.z = fmaf(w3, r3.z, a.z); a.w = fmaf(w3, r3.w, a.w);
  }
  float inv = (n > 0 && den > 0.f) ? 1.f / den : 0.f;
  a.x *= inv; a.y *= inv; a.z *= inv; a.w *= inv;
  *(float4*)(y + (size_t)s * D + g * 4) = a;
}

// ---------- DIAGNOSTIC CLONES (repeat=3, dummy outputs, counter probes) ----

// (a) R4 means clone. rep-seeded acc + per-rep memory clobber defeat CSE/DCE.
__global__ void k_means_diag(const float* __restrict__ x, const int* __restrict__ starts,
                             float* __restrict__ dum, int S, int repeat) {
  int tid = blockIdx.x * blockDim.x + threadIdx.x;
  if (tid >= S * 32) return;
  int s = tid >> 5, g = tid & 31;
  for (int rep = 0; rep < repeat; ++rep) {
    asm volatile("" ::: "memory");
    int b = starts[s], e = starts[s + 1];
    int n = e - b;
    const float4* xp = (const float4*)(x + (size_t)b * D) + g;
    float4 a = make_float4((float)rep, 0.f, 0.f, 0.f);
    for (int v = 0; v < n; v += 4) {
      int rem = n - v;
      const float4* p = xp + (size_t)v * (D / 4);
      float4 r0 = p[0];
      float4 r1 = p[(rem > 1) ? (D / 4) : 0];
      float4 r2 = p[(rem > 2) ? (2 * D / 4) : 0];
      float4 r3 = p[(rem > 3) ? (3 * D / 4) : 0];
      float m1 = (rem > 1) ? 1.f : 0.f;
      float m2 = (rem > 2) ? 1.f : 0.f;
      float m3 = (rem > 3) ? 1.f : 0.f;
      a.x += r0.x; a.y += r0.y; a.z += r0.z; a.w += r0.w;
      a.x = fmaf(m1, r1.x, a.x); a.y = fmaf(m1, r1.y, a.y);
      a.z = fmaf(m1, r1.z, a.z); a.w = fmaf(m1, r1.w, a.w);
      a.x = fmaf(m2, r2.x, a.x); a.y = fmaf(m2, r2.y, a.y);
      a.z = fmaf(m2, r2.z, a.z); a.w = fmaf(m2, r2.w, a.w);
      a.x = fmaf(m3, r3.x, a.x); a.y = fmaf(m3, r3.y, a.y);
      a.z = fmaf(m3, r3.z, a.z); a.w = fmaf(m3, r3.w, a.w);
    }
    float inv = (n > 0) ? 1.f / (float)n : 0.f;
    a.x *= inv; a.y *= inv; a.z *= inv; a.w *= inv;
    *(float4*)(dum + (size_t)s * D + g * 4) = a;
  }
}

// (b) 2-interleaved-segment means: doubles independent load chains per thread.
// Direct test of the latency hypothesis (expect ~0.6x of (a) if latency-bound).
__global__ void k_means2_diag(const float* __restrict__ x, const int* __restrict__ starts,
                              float* __restrict__ dum, int S, int repeat) {
  int tid = blockIdx.x * blockDim.x + threadIdx.x;
  int half = (S + 1) / 2;
  if (tid >= half * 32) return;
  int sA = tid >> 5, g = tid & 31;
  int sB = sA + half;
  for (int rep = 0; rep < repeat; ++rep) {
    asm volatile("" ::: "memory");
    int bA = starts[sA], nA = starts[sA + 1] - bA;
    int bB = 0, nB = 0;
    if (sB < S) { bB = starts[sB]; nB = starts[sB + 1] - bB; }
    const float4* xA = (const float4*)(x + (size_t)bA * D) + g;
    const float4* xB = (const float4*)(x + (size_t)bB * D) + g;
    float4 a = make_float4((float)rep, 0.f, 0.f, 0.f);
    float4 bq = make_float4((float)rep, 0.f, 0.f, 0.f);
    int nmax = nA > nB ? nA : nB;
    for (int v = 0; v < nmax; v += 2) {
      float4 rA0 = xA[(size_t)(v     < nA ? v     : 0) * (D / 4)];
      float4 rB0 = xB[(size_t)(v     < nB ? v     : 0) * (D / 4)];
      float4 rA1 = xA[(size_t)(v + 1 < nA ? v + 1 : 0) * (D / 4)];
      float4 rB1 = xB[(size_t)(v + 1 < nB ? v + 1 : 0) * (D / 4)];
      float mA0 = (v < nA) ? 1.f : 0.f, mA1 = (v + 1 < nA) ? 1.f : 0.f;
      float mB0 = (v < nB) ? 1.f : 0.f, mB1 = (v + 1 < nB) ? 1.f : 0.f;
      a.x = fmaf(mA0, rA0.x, a.x); a.y = fmaf(mA0, rA0.y, a.y);
      a.z = fmaf(mA0, rA0.z, a.z); a.w = fmaf(mA0, rA0.w, a.w);
      bq.x = fmaf(mB0, rB0.x, bq.x); bq.y = fmaf(mB0, rB0.y, bq.y);
      bq.z = fmaf(mB0, rB0.z, bq.z); bq.w = fmaf(mB0, rB0.w, bq.w);
      a.x = fmaf(mA1, rA1.x, a.x); a.y = fmaf(mA1, rA1.y, a.y);
      a.z = fmaf(mA1, rA1.z, a.z); a.w = fmaf(mA1, rA1.w, a.w);
      bq.x = fmaf(mB1, rB1.x, bq.x); bq.y = fmaf(mB1, rB1.y, bq.y);
      bq.z = fmaf(mB1, rB1.z, bq.z); bq.w = fmaf(mB1, rB1.w, bq.w);
    }
    float invA = (nA > 0) ? 1.f / (float)nA : 0.f;
    a.x *= invA; a.y *= invA; a.z *= invA; a.w *= invA;
    *(float4*)(dum + (size_t)sA * D + g * 4) = a;
    if (sB < S) {
      float invB = (nB > 0) ? 1.f / (float)nB : 0.f;
      bq.x *= invB; bq.y *= invB; bq.z *= invB; bq.w *= invB;
      *(float4*)(dum + (size_t)sB * D + g * 4) = bq;
    }
  }
}

// (c) R4 score_y clone; t = poisoned ws (~ -3e-13 -> exp ~= 1, no inf).
__global__ void k_score_y_diag(const float* __restrict__ x, const int* __restrict__ starts,
                               const float* __restrict__ t, float* __restrict__ dum,
                               int S, int repeat) {
  int tid = blockIdx.x * blockDim.x + threadIdx.x;
  if (tid >= S * 32) return;
  int s = tid >> 5, g = tid & 31;
  for (int rep = 0; rep < repeat; ++rep) {
    asm volatile("" ::: "memory");
    int b = starts[s], e = starts[s + 1];
    int n = e - b;
    float4 t4 = *(const float4*)(t + (size_t)s * D + g * 4);
    const float4* xp = (const float4*)(x + (size_t)b * D) + g;
    float4 a = make_float4((float)rep * 1e-30f, 0.f, 0.f, 0.f);
    float den = (float)rep * 1e-30f;
    for (int v = 0; v < n; v += 4) {
      int rem = n - v;
      const float4* p = xp + (size_t)v * (D / 4);
      float4 r0 = p[0];
      float4 r1 = p[(rem > 1) ? (D / 4) : 0];
      float4 r2 = p[(rem > 2) ? (2 * D / 4) : 0];
      float4 r3 = p[(rem > 3) ? (3 * D / 4) : 0];
      float d0 = t4.x * r0.x + t4.y * r0.y + t4.z * r0.z + t4.w * r0.w;
      float d1 = t4.x * r1.x + t4.y * r1.y + t4.z * r1.z + t4.w * r1.w;
      float d2 = t4.x * r2.x + t4.y * r2.y + t4.z * r2.z + t4.w * r2.w;
      float d3 = t4.x * r3.x + t4.y * r3.y + t4.z * r3.z + t4.w * r3.w;
      d0 += __shfl_xor(d0, 16); d1 += __shfl_xor(d1, 16);
      d2 += __shfl_xor(d2, 16); d3 += __shfl_xor(d3, 16);
      d0 += __shfl_xor(d0, 8);  d1 += __shfl_xor(d1, 8);
      d2 += __shfl_xor(d2, 8);  d3 += __shfl_xor(d3, 8);
      d0 += __shfl_xor(d0, 4);  d1 += __shfl_xor(d1, 4);
      d2 += __shfl_xor(d2, 4);  d3 += __shfl_xor(d3, 4);
      d0 += __shfl_xor(d0, 2);  d1 += __shfl_xor(d1, 2);
      d2 += __shfl_xor(d2, 2);  d3 += __shfl_xor(d3, 2);
      d0 += __shfl_xor(d0, 1);  d1 += __shfl_xor(d1, 1);
      d2 += __shfl_xor(d2, 1);  d3 += __shfl_xor(d3, 1);
      float w0 = __expf(d0);
      float w1 = (rem > 1) ? __expf(d1) : 0.f;
      float w2 = (rem > 2) ? __expf(d2) : 0.f;
      float w3 = (rem > 3) ? __expf(d3) : 0.f;
      den += w0 + w1 + w2 + w3;
      a.x = fmaf(w0, r0.x, a.x); a.y = fmaf(w0, r0.y, a.y);
      a.z = fmaf(w0, r0.z, a.z); a.w = fmaf(w0, r0.w, a.w);
      a.x = fmaf(w1, r1.x, a.x); a.y = fmaf(w1, r1.y, a.y);
      a.z = fmaf(w1, r1.z, a.z); a.w = fmaf(w1, r1.w, a.w);
      a.x = fmaf(w2, r2.x, a.x); a.y = fmaf(w2, r2.y, a.y);
      a.z = fmaf(w2, r2.z, a.z); a.w = fmaf(w2, r2.w, a.w);
      a.x = fmaf(w3, r3.x, a.x); a.y = fmaf(w3, r3.y, a.y);
      a.z = fmaf(w3, r3.z, a.z); a.w = fmaf(w3, r3.w, a.w);
    }
    float inv = (n > 0 && den > 0.f) ? 1.f / den : 0.f;
    a.x *= inv; a.y *= inv; a.z *= inv; a.w *= inv;
    *(float4*)(dum + (size_t)s * D + g * 4) = a;
  }
}

extern "C" void kernel_launch(void* const* d_in, const int* in_sizes, int n_in,
                              void* d_out, int out_size, void* d_ws, size_t ws_size,
                              hipStream_t stream) {
  const float* x = (const float*)d_in[0];
  const int* idx = (const int*)d_in[1];
  const float* Wq = (const float*)d_in[3];
  const float* Wk = (const float*)d_in[4];
  const float* Wo = (const float*)d_in[5];
  float* out = (float*)d_out;
  const int V = in_sizes[1];
  const int S = out_size / D;

  char* ws = (char*)d_ws;
  float* M = (float*)(ws + 0);        // 64 KB
  float* WoT = (float*)(ws + 65536);  // 64 KB
  int* starts = (int*)(ws + 131072);  // (S+1)*4 B
  size_t base = (131072 + 4 * (size_t)(S + 1) + 255) & ~(size_t)255;
  size_t SD = (size_t)S * D;
  float* mean = (float*)(ws + base);       // dead after rowmat #1; alias y
  float* y = mean;
  float* t = mean + SD;                    // live until k_score_y
  float* dum1 = mean + 2 * SD;             // diag outputs
  float* dum2 = mean + 3 * SD;
  float* dum_t = mean + 4 * SD;            // poisoned, read-only (exp(~0)=1)

  const int sgBlocks = (int)((S * 32 + 255) / 256);
  const int rmBlocks = ((S + 3) / 4 * 32 + 255) / 256;

  hipLaunchKernelGGL(k_prep, dim3(D), dim3(D), 0, stream, Wq, Wk, Wo, M, WoT);
  hipLaunchKernelGGL(k_starts, dim3((V + 255) / 256), dim3(256), 0, stream, idx, starts, V, S);

  // ---- diagnostics (repeat=3, dummy outputs) ----
  hipLaunchKernelGGL(k_means_diag, dim3(sgBlocks), dim3(256), 0, stream, x, starts, dum1, S, 3);
  {
    int half = (S + 1) / 2;
    int blocks = (half * 32 + 255) / 256;
    hipLaunchKernelGGL(k_means2_diag, dim3(blocks), dim3(256), 0, stream, x, starts, dum1, S, 3);
  }
  hipLaunchKernelGGL(k_score_y_diag, dim3(sgBlocks), dim3(256), 0, stream, x, starts, dum_t, dum2, S, 3);

  // ---- real pipeline (R4 verbatim) ----
  hipLaunchKernelGGL(k_means, dim3(sgBlocks), dim3(256), 0, stream, x, starts, mean, S);
  hipLaunchKernelGGL(k_rowmat4, dim3(rmBlocks), dim3(256), 0, stream, mean, M, t, S);
  hipLaunchKernelGGL(k_score_y, dim3(sgBlocks), dim3(256), 0, stream, x, starts, t, y, S);
  hipLaunchKernelGGL(k_rowmat4, dim3(rmBlocks), dim3(256), 0, stream, y, WoT, out, S);
}